// Round 1
// baseline (165.372 us; speedup 1.0000x reference)
//
#include <hip/hip_runtime.h>

#define T_TOK 512
#define BINS 50
#define FRAMES 3000
#define FQ (FRAMES / 4)   // 750 float4 groups per row
#define C_EN 640
#define C_ASR 512

// Kernel 1: per-batch duration + inclusive scan + frame->token map.
// One block per batch, 512 threads (one per token).
__global__ __launch_bounds__(T_TOK) void k_dur(
    const float* __restrict__ dur_logits,  // [B,512,50]
    const int*   __restrict__ amask,       // [B,512]
    const float* __restrict__ speed,       // [1]
    float* __restrict__ out,               // full output base (float32)
    int*   __restrict__ tok_map,           // [B,3000] workspace
    int B)
{
    const int b    = blockIdx.x;
    const int t    = threadIdx.x;
    const int lane = t & 63;
    const int wid  = t >> 6;

    __shared__ float cs[T_TOK];
    __shared__ float wsum[8];

    const float spd = speed[0];
    const float* L = dur_logits + ((size_t)(b * T_TOK + t)) * BINS;
    float s = 0.0f;
#pragma unroll
    for (int i = 0; i < BINS; ++i)
        s += 1.0f / (1.0f + expf(-L[i]));
    float dur  = s / spd;
    float pred = fmaxf(rintf(dur), 1.0f) * (float)amask[b * T_TOK + t];

    // ---- inclusive scan over 512 tokens (wave scan + cross-wave) ----
    float v = pred;
#pragma unroll
    for (int off = 1; off < 64; off <<= 1) {
        float u = __shfl_up(v, off, 64);
        if (lane >= off) v += u;
    }
    if (lane == 63) wsum[wid] = v;
    __syncthreads();
    if (t < 8) {
        float w = wsum[t];
#pragma unroll
        for (int off = 1; off < 8; off <<= 1) {
            float u = __shfl_up(w, off, 64);
            if (t >= off) w += u;
        }
        wsum[t] = w;
    }
    __syncthreads();
    float incl = v + (wid ? wsum[wid - 1] : 0.0f);
    cs[t] = incl;
    __syncthreads();

    // ---- scalar outputs ----
    const size_t asr_n = (size_t)B * C_ASR * FRAMES;
    const size_t en_n  = (size_t)B * C_EN * FRAMES;
    float* out_audio = out + asr_n + en_n;       // [B]
    float* out_pred  = out_audio + B;            // [B,512]
    out_pred[b * T_TOK + t] = pred;
    const float total = cs[T_TOK - 1];
    if (t == 0) {
        // jnp cast f32->int32 truncates; value is an exact integer < 2^24*? (fits f32)
        out_audio[b] = (float)(int)(total * 600.0f);
    }

    // ---- frame -> token map: first idx with cs[idx] > f ----
    for (int f = t; f < FRAMES; f += T_TOK) {
        int tok = -1;
        float ff = (float)f;
        if (ff < total) {
            int lo = 0, hi = T_TOK - 1;
            while (lo < hi) {
                int mid = (lo + hi) >> 1;
                if (cs[mid] > ff) hi = mid; else lo = mid + 1;
            }
            tok = lo;
        }
        tok_map[b * FRAMES + f] = tok;
    }
}

// Kernel 2: gather both outputs, one float4 (4 frames) per thread.
__global__ __launch_bounds__(256) void k_gather(
    const float* __restrict__ dmat,     // [B,512,640]
    const float* __restrict__ t_en,     // [B,512,512]
    const int*   __restrict__ tok_map,  // [B,3000]
    float* __restrict__ out, int B)
{
    const int ASRQ = B * C_ASR * FQ;   // float4 count for asr
    const int ENQ  = B * C_EN * FQ;
    int idx = blockIdx.x * 256 + threadIdx.x;

    if (idx < ASRQ) {
        int b  = idx / (C_ASR * FQ);
        int r  = idx - b * (C_ASR * FQ);
        int c  = r / FQ;
        int fq = r - c * FQ;
        int4 tk = reinterpret_cast<const int4*>(tok_map)[b * FQ + fq];
        const float* row = t_en + ((size_t)b * C_ASR + c) * T_TOK;
        float4 o;
        o.x = (tk.x >= 0) ? row[tk.x] : 0.0f;
        o.y = (tk.y >= 0) ? row[tk.y] : 0.0f;
        o.z = (tk.z >= 0) ? row[tk.z] : 0.0f;
        o.w = (tk.w >= 0) ? row[tk.w] : 0.0f;
        reinterpret_cast<float4*>(out)[idx] = o;
    } else if (idx < ASRQ + ENQ) {
        int j  = idx - ASRQ;
        int b  = j / (C_EN * FQ);
        int r  = j - b * (C_EN * FQ);
        int c  = r / FQ;
        int fq = r - c * FQ;
        int4 tk = reinterpret_cast<const int4*>(tok_map)[b * FQ + fq];
        const float* dm = dmat + (size_t)b * T_TOK * C_EN + c;
        float4 o;
        o.x = (tk.x >= 0) ? dm[(size_t)tk.x * C_EN] : 0.0f;
        o.y = (tk.y >= 0) ? dm[(size_t)tk.y * C_EN] : 0.0f;
        o.z = (tk.z >= 0) ? dm[(size_t)tk.z * C_EN] : 0.0f;
        o.w = (tk.w >= 0) ? dm[(size_t)tk.w * C_EN] : 0.0f;
        reinterpret_cast<float4*>(out + (size_t)ASRQ * 4)[j] = o;
    }
}

extern "C" void kernel_launch(void* const* d_in, const int* in_sizes, int n_in,
                              void* d_out, int out_size, void* d_ws, size_t ws_size,
                              hipStream_t stream) {
    const float* dmat       = (const float*)d_in[0];  // [B,512,640]
    const float* t_en       = (const float*)d_in[1];  // [B,512,512]
    const float* dur_logits = (const float*)d_in[2];  // [B,512,50]
    const int*   amask      = (const int*)d_in[3];    // [B,512]
    const float* speed      = (const float*)d_in[4];  // [1]
    float* out = (float*)d_out;

    int B = in_sizes[3] / T_TOK;
    int* tok_map = (int*)d_ws;  // B*3000 ints

    k_dur<<<B, T_TOK, 0, stream>>>(dur_logits, amask, speed, out, tok_map, B);

    int total_q = B * C_ASR * FQ + B * C_EN * FQ;
    k_gather<<<(total_q + 255) / 256, 256, 0, stream>>>(dmat, t_en, tok_map, out, B);
}